// Round 1
// baseline (1066.396 us; speedup 1.0000x reference)
//
#include <hip/hip_runtime.h>
#include <cmath>

// ---------------------------------------------------------------------------
// InteractiveGallingModelV5: B=65536 independent rollouts, NC=256 sequential
// cycles. One thread per rollout; loop over cycles. All math mimics XLA-CPU
// f32 evaluation op-by-op (no FMA contraction, XLA tanh polynomial, logistic
// expansion, correctly-rounded exp/pow via f64) because two output rows are
// 0/1 indicators of float comparisons -- a single decision flip vs the
// reference is an absmax error of 1.0.
// ---------------------------------------------------------------------------

__device__ __forceinline__ float exp_cr(float x) {
#pragma clang fp contract(off)
  // correctly-rounded f32 exp via f64 (OCML f64 exp err ~1 ulp in double,
  // which is far below f32 rounding granularity)
  return (float)exp((double)x);
}

__device__ __forceinline__ float sigmoid_ref(float x) {
#pragma clang fp contract(off)
  // XLA LogisticExpander: 1 / (1 + exp(-x)), f32 add + IEEE f32 divide
  float e = exp_cr(-x);
  float d = 1.0f + e;
  return 1.0f / d;
}

__device__ __forceinline__ float tanh_xla(float x) {
#pragma clang fp contract(off)
  // XLA EmitTanh F32 rational approximation (same on CPU and GPU backends)
  float ax = fabsf(x);
  float xc = fminf(fmaxf(x, -7.90531110763549805f), 7.90531110763549805f);
  float x2 = xc * xc;
  float p = -2.76076847742355e-16f;
  p = p * x2 + 2.00018790482477e-13f;
  p = p * x2 + (-8.60467152213735e-11f);
  p = p * x2 + 5.12229709037114e-08f;
  p = p * x2 + 1.48572235717979e-05f;
  p = p * x2 + 6.37261928875436e-04f;
  p = p * x2 + 4.89352455891786e-03f;
  p = xc * p;
  float q = 1.19825839466702e-06f;
  q = q * x2 + 1.18534705686654e-04f;
  q = q * x2 + 2.26843463243900e-03f;
  q = q * x2 + 4.89352518554385e-03f;
  float approx = p / q;
  return (ax < 0.0004f) ? x : approx;
}

__device__ __forceinline__ float pow_cr(float x, float y) {
  // correctly-rounded f32 pow via f64 (matches glibc powf, which is near-CR)
  return (float)pow((double)x, (double)y);
}

__global__ __launch_bounds__(256) void galling_kernel(
    const float* __restrict__ params,
    const float* __restrict__ M_init,
    const float* __restrict__ rho_init,
    const float* __restrict__ T_arr,
    const float* __restrict__ u_growth,
    const float* __restrict__ u_detach,
    const float* __restrict__ u_sev,
    const float* __restrict__ noise,
    float* __restrict__ out,
    int B, int NC)
{
#pragma clang fp contract(off)
  int b = blockIdx.x * blockDim.x + threadIdx.x;
  if (b >= B) return;

  const float k_adh        = params[0];
  const float alpha_tau    = params[1];
  const float p_growth_base= params[2];
  const float s_peak       = params[3];
  const float s_base       = params[4];
  const float decay_rate   = params[5];
  const float p_detach_base= params[6];
  const float M_half       = params[7];
  const float c_stick      = params[8];
  const float f_min        = params[9];
  const float f_max        = params[10];
  const float M_sat        = params[11];
  const float rho_crit     = params[12];
  const float beta_sharp   = params[13];

  const float T  = T_arr[0];
  const float dT = T - 165.0f;                       // T_REF
  const float softening = exp_cr(0.2f * dT);
  float pg = (p_growth_base * softening) / (1.0f + softening);
  const float p_growth = fminf(fmaxf(pg, 0.01f), 0.99f);
  const float h_T  = exp_cr((-c_stick) * dT);
  const float ks   = k_adh * softening;              // constant-folded in ref too
  const float fspan = f_max - f_min;                 // constant-folded in ref

  float M   = M_init[b];
  float rho = rho_init[b];
  float mu  = 0.15f;                                 // MU_LOW
  // beta at loop top == sigmoid(beta_sharp*(rho - rho_crit)); carried across
  // iterations (bit-identical to recomputing from rho_next each step).
  float beta = sigmoid_ref(beta_sharp * (rho - rho_crit));

  const long long Bs = (long long)B;
  const long long R  = (long long)NC * Bs;           // per-row stride in out

  for (int c = 0; c < NC; ++c) {
    long long idx = (long long)c * Bs + b;
    float ug = u_growth[idx];
    float ud = u_detach[idx];
    float us = u_sev[idx];
    float nz = noise[idx];

    bool growth = ug < p_growth;
    // ((4*beta)*(1-beta))*s_peak + s_base  (left-assoc, no FMA)
    float state_scale = ((4.0f * beta) * (1.0f - beta)) * s_peak + s_base;
    float dMg = (ks * pow_cr(mu, alpha_tau)) * state_scale;
    dMg = growth ? dMg : 0.0f;
    float g_M = M / ((M + M_half) + 1e-6f);
    float p_det = fminf(fmaxf((p_detach_base * g_M) * h_T, 0.0f), 0.95f);
    bool det = ud < p_det;
    float sev = f_min + us * fspan;
    float Mn = (M + dMg) - decay_rate * M;
    Mn = det ? Mn * (1.0f - sev) : Mn;
    Mn = fmaxf(Mn, 0.0f);
    float rhon  = tanh_xla(Mn / M_sat);
    float betan = sigmoid_ref(beta_sharp * (rhon - rho_crit));
    float mun = (1.0f - betan) * 0.15f + betan * 1.0f;  // MU_LOW / MU_HIGH
    mun = fminf(fmaxf(mun + nz * 0.005f, 0.1f), 1.3f);  // KDE_SMOOTHING

    long long ob = (long long)c * Bs + b;
    out[ob        ] = mun;
    out[ob +   R  ] = rhon;
    out[ob + 2*R  ] = Mn;
    out[ob + 3*R  ] = betan;
    out[ob + 4*R  ] = p_growth;
    out[ob + 5*R  ] = p_det;
    out[ob + 6*R  ] = growth ? 1.0f : 0.0f;
    out[ob + 7*R  ] = det ? 1.0f : 0.0f;

    M = Mn; rho = rhon; mu = mun; beta = betan;
  }
}

extern "C" void kernel_launch(void* const* d_in, const int* in_sizes, int n_in,
                              void* d_out, int out_size, void* d_ws, size_t ws_size,
                              hipStream_t stream) {
  const float* params   = (const float*)d_in[0];
  const float* M_init   = (const float*)d_in[1];
  const float* rho_init = (const float*)d_in[2];
  const float* T_arr    = (const float*)d_in[3];
  const float* u_growth = (const float*)d_in[4];
  const float* u_detach = (const float*)d_in[5];
  const float* u_sev    = (const float*)d_in[6];
  const float* noise    = (const float*)d_in[7];
  float* out = (float*)d_out;

  int B  = in_sizes[1];                 // 65536
  int NC = in_sizes[4] / B;             // 256

  int block = 256;
  int grid  = (B + block - 1) / block;  // 256 blocks
  galling_kernel<<<grid, block, 0, stream>>>(params, M_init, rho_init, T_arr,
                                             u_growth, u_detach, u_sev, noise,
                                             out, B, NC);
}

// Round 2
// 900.765 us; speedup vs baseline: 1.1839x; 1.1839x over previous
//
#include <hip/hip_runtime.h>
#include <cmath>

// ---------------------------------------------------------------------------
// InteractiveGallingModelV5: B=65536 independent rollouts, NC=256 sequential
// cycles. One thread per rollout. Latency-bound at 1 wave/SIMD (wave count is
// structurally capped by B), so the optimization target is the per-iteration
// dependent-chain length.
//
// R1 change: jax.nn.sigmoid goes through XLA's LogisticExpander =
// 0.5 + 0.5*tanh(0.5*x) -- NOT 1/(1+exp(-x)). Use the XLA tanh rational
// polynomial for it (pure f32), removing the f64 exp from the loop chain.
// pow stays f64-correctly-rounded (matches glibc powf bit-exactly).
// ---------------------------------------------------------------------------

__device__ __forceinline__ float exp_cr(float x) {
#pragma clang fp contract(off)
  return (float)exp((double)x);   // scalar setup only (p_growth, h_T)
}

__device__ __forceinline__ float tanh_xla(float x) {
#pragma clang fp contract(off)
  // XLA EmitTanh F32 rational approximation
  float ax = fabsf(x);
  float xc = fminf(fmaxf(x, -7.90531110763549805f), 7.90531110763549805f);
  float x2 = xc * xc;
  float p = -2.76076847742355e-16f;
  p = p * x2 + 2.00018790482477e-13f;
  p = p * x2 + (-8.60467152213735e-11f);
  p = p * x2 + 5.12229709037114e-08f;
  p = p * x2 + 1.48572235717979e-05f;
  p = p * x2 + 6.37261928875436e-04f;
  p = p * x2 + 4.89352455891786e-03f;
  p = xc * p;
  float q = 1.19825839466702e-06f;
  q = q * x2 + 1.18534705686654e-04f;
  q = q * x2 + 2.26843463243900e-03f;
  q = q * x2 + 4.89352518554385e-03f;
  float approx = p / q;
  return (ax < 0.0004f) ? x : approx;
}

__device__ __forceinline__ float sigmoid_xla(float x) {
#pragma clang fp contract(off)
  // XLA LogisticExpander: logistic(x) = 0.5 + 0.5 * tanh(0.5 * x)
  return 0.5f + 0.5f * tanh_xla(0.5f * x);
}

__device__ __forceinline__ float pow_cr(float x, float y) {
  // correctly-rounded f32 pow via f64 (matches glibc powf, which is CR)
  return (float)pow((double)x, (double)y);
}

__global__ __launch_bounds__(256) void galling_kernel(
    const float* __restrict__ params,
    const float* __restrict__ M_init,
    const float* __restrict__ rho_init,
    const float* __restrict__ T_arr,
    const float* __restrict__ u_growth,
    const float* __restrict__ u_detach,
    const float* __restrict__ u_sev,
    const float* __restrict__ noise,
    float* __restrict__ out,
    int B, int NC)
{
#pragma clang fp contract(off)
  int b = blockIdx.x * blockDim.x + threadIdx.x;
  if (b >= B) return;

  const float k_adh        = params[0];
  const float alpha_tau    = params[1];
  const float p_growth_base= params[2];
  const float s_peak       = params[3];
  const float s_base       = params[4];
  const float decay_rate   = params[5];
  const float p_detach_base= params[6];
  const float M_half       = params[7];
  const float c_stick      = params[8];
  const float f_min        = params[9];
  const float f_max        = params[10];
  const float M_sat        = params[11];
  const float rho_crit     = params[12];
  const float beta_sharp   = params[13];

  const float T  = T_arr[0];
  const float dT = T - 165.0f;                       // T_REF
  const float softening = exp_cr(0.2f * dT);
  float pg = (p_growth_base * softening) / (1.0f + softening);
  const float p_growth = fminf(fmaxf(pg, 0.01f), 0.99f);
  const float h_T  = exp_cr((-c_stick) * dT);
  const float ks   = k_adh * softening;
  const float fspan = f_max - f_min;

  float M   = M_init[b];
  float rho = rho_init[b];
  float mu  = 0.15f;                                 // MU_LOW
  float beta = sigmoid_xla(beta_sharp * (rho - rho_crit));

  const long long Bs = (long long)B;
  const long long R  = (long long)NC * Bs;           // per-row stride in out

  // input prefetch double-buffer: issue iter c+1 loads before iter c's chain
  long long idx0 = b;
  float ug = u_growth[idx0];
  float ud = u_detach[idx0];
  float us = u_sev[idx0];
  float nz = noise[idx0];

  for (int c = 0; c < NC; ++c) {
    float ug_n = 0.f, ud_n = 0.f, us_n = 0.f, nz_n = 0.f;
    if (c + 1 < NC) {
      long long idxn = (long long)(c + 1) * Bs + b;
      ug_n = u_growth[idxn];
      ud_n = u_detach[idxn];
      us_n = u_sev[idxn];
      nz_n = noise[idxn];
    }

    bool growth = ug < p_growth;
    float state_scale = ((4.0f * beta) * (1.0f - beta)) * s_peak + s_base;
    float dMg = (ks * pow_cr(mu, alpha_tau)) * state_scale;
    dMg = growth ? dMg : 0.0f;
    float g_M = M / ((M + M_half) + 1e-6f);
    float p_det = fminf(fmaxf((p_detach_base * g_M) * h_T, 0.0f), 0.95f);
    bool det = ud < p_det;
    float sev = f_min + us * fspan;
    float Mn = (M + dMg) - decay_rate * M;
    Mn = det ? Mn * (1.0f - sev) : Mn;
    Mn = fmaxf(Mn, 0.0f);
    float rhon  = tanh_xla(Mn / M_sat);
    float betan = sigmoid_xla(beta_sharp * (rhon - rho_crit));
    float mun = (1.0f - betan) * 0.15f + betan * 1.0f;  // MU_LOW / MU_HIGH
    mun = fminf(fmaxf(mun + nz * 0.005f, 0.1f), 1.3f);  // KDE_SMOOTHING

    long long ob = (long long)c * Bs + b;
    out[ob        ] = mun;
    out[ob +   R  ] = rhon;
    out[ob + 2*R  ] = Mn;
    out[ob + 3*R  ] = betan;
    out[ob + 4*R  ] = p_growth;
    out[ob + 5*R  ] = p_det;
    out[ob + 6*R  ] = growth ? 1.0f : 0.0f;
    out[ob + 7*R  ] = det ? 1.0f : 0.0f;

    M = Mn; rho = rhon; mu = mun; beta = betan;
    ug = ug_n; ud = ud_n; us = us_n; nz = nz_n;
  }
}

extern "C" void kernel_launch(void* const* d_in, const int* in_sizes, int n_in,
                              void* d_out, int out_size, void* d_ws, size_t ws_size,
                              hipStream_t stream) {
  const float* params   = (const float*)d_in[0];
  const float* M_init   = (const float*)d_in[1];
  const float* rho_init = (const float*)d_in[2];
  const float* T_arr    = (const float*)d_in[3];
  const float* u_growth = (const float*)d_in[4];
  const float* u_detach = (const float*)d_in[5];
  const float* u_sev    = (const float*)d_in[6];
  const float* noise    = (const float*)d_in[7];
  float* out = (float*)d_out;

  int B  = in_sizes[1];                 // 65536
  int NC = in_sizes[4] / B;             // 256

  int block = 256;
  int grid  = (B + block - 1) / block;  // 256 blocks
  galling_kernel<<<grid, block, 0, stream>>>(params, M_init, rho_init, T_arr,
                                             u_growth, u_detach, u_sev, noise,
                                             out, B, NC);
}